// Round 21
// baseline (189.750 us; speedup 1.0000x reference)
//
#include <hip/hip_runtime.h>

#define F 128
#define CLSN 40
#define NFINE_MAX 256
#define PCAP 10240
#define TILE 4096
#define STAGE_CAP 10240
#define QSCALE 22.0f

typedef __attribute__((ext_vector_type(8))) short short8v;
typedef __attribute__((ext_vector_type(4))) float float4v;

static __device__ inline ushort f2bf(float f) {
  uint u = __float_as_uint(f);
  uint r = (u + 0x7FFFu + ((u >> 16) & 1u)) >> 16;
  return (ushort)r;
}
static __device__ inline float bfLo(uint u) { return __uint_as_float(u << 16); }
static __device__ inline float bfHi(uint u) { return __uint_as_float(u & 0xFFFF0000u); }
static __device__ inline int sb(uint v, int sh) { return (int)(signed char)(v >> sh); }
static __device__ inline unsigned char q8(float f) {
  float t = rintf(f * QSCALE);
  t = fminf(fmaxf(t, -127.f), 127.f);
  return (unsigned char)(signed char)(int)t;
}
static __device__ inline unsigned char q8s(float f, float qs) {
  float t = rintf(f * qs);
  t = fminf(fmaxf(t, -127.f), 127.f);
  return (unsigned char)(signed char)(int)t;
}
// per-wave max over per-block maxima; MUST be called with all 64 lanes active.
static __device__ inline float wave_max_bmax(const float* __restrict__ bmax, int nb,
                                             int lane) {
  float mx = 0.f;
  for (int i = lane; i < nb; i += 64) mx = fmaxf(mx, bmax[i]);
#pragma unroll
  for (int d = 32; d; d >>= 1) mx = fmaxf(mx, __shfl_xor(mx, d));
  return mx;
}

// ---------------- fused prep: cast x (bf16 + int8), pack weights, init cursors -------
__global__ __launch_bounds__(256) void k_prep(const float* __restrict__ x,
                                              ushort* __restrict__ xb,
                                              unsigned char* __restrict__ xq,
                                              const float* __restrict__ Wl1,
                                              const float* __restrict__ Wr1,
                                              ushort* __restrict__ Wp1,
                                              const float* __restrict__ Wl2,
                                              const float* __restrict__ Wr2,
                                              ushort* __restrict__ Wpl,
                                              ushort* __restrict__ Wpr,
                                              int* __restrict__ fcur,
                                              int nelem4, int castBlocks, int nfine) {
  const int blk = blockIdx.x;
  if (blk < castBlocks) {
    int i = blk * 256 + threadIdx.x;
    if (i < nelem4) {
      float4 v = reinterpret_cast<const float4*>(x)[i];
      ushort4 o;
      o.x = f2bf(v.x); o.y = f2bf(v.y); o.z = f2bf(v.z); o.w = f2bf(v.w);
      reinterpret_cast<ushort4*>(xb)[i] = o;
      uchar4 q;
      q.x = q8(v.x); q.y = q8(v.y); q.z = q8(v.z); q.w = q8(v.w);
      reinterpret_cast<uchar4*>(xq)[i] = q;
    }
  } else if (blk < castBlocks + 16) {
    int t = (blk - castBlocks) * 256 + threadIdx.x;
    int lane = t & 63, f = (t >> 6) & 7, ks = t >> 9;
    int col = f * 16 + (lane & 15);
    int k0 = ks * 32 + (lane >> 4) * 8;
#pragma unroll
    for (int j = 0; j < 8; ++j) {
      int k = k0 + j;
      float w = (k < 128) ? Wl1[k * 128 + col] : Wr1[(k - 128) * 128 + col];
      Wp1[t * 8 + j] = f2bf(w);
    }
  } else if (blk < castBlocks + 22) {
    int t = (blk - castBlocks - 16) * 256 + threadIdx.x;
    const float* W = (t < 768) ? Wl2 : Wr2;
    ushort* Wp = (t < 768) ? Wpl : Wpr;
    int tt = (t < 768) ? t : t - 768;
    int lane = tt & 63, rem = tt >> 6;
    int f = rem % 3, ks = rem / 3;
    int col = f * 16 + (lane & 15);
    int k0 = ks * 32 + (lane >> 4) * 8;
#pragma unroll
    for (int j = 0; j < 8; ++j) {
      int k = k0 + j;
      float w = (col < CLSN) ? W[k * CLSN + col] : 0.f;
      Wp[tt * 8 + j] = f2bf(w);
    }
  } else {
    int i = threadIdx.x;
    if (i < nfine) fcur[i] = i * PCAP;
  }
}

// ---------------- one-pass tiled radix partition into fine buckets ----------------
__global__ __launch_bounds__(256) void k_partition(const int* __restrict__ src,
                                                   const int* __restrict__ dst,
                                                   int* __restrict__ fcur,
                                                   uint* __restrict__ pairs, int E) {
  __shared__ int hh[NFINE_MAX];
  __shared__ int bb[NFINE_MAX];
  __shared__ unsigned char ebkt[TILE];
  __shared__ ushort dlow[TILE];
  const int tid = threadIdx.x;
  const int tile0 = blockIdx.x * TILE;
  const int lim = min(TILE, E - tile0);
  for (int i = tid; i < NFINE_MAX; i += 256) hh[i] = 0;
  __syncthreads();
  for (int i = tid; i < lim; i += 256) {
    int d = dst[tile0 + i];
    int b = d >> 9;
    ebkt[i] = (unsigned char)b;
    dlow[i] = (ushort)(d & 511);
    atomicAdd(&hh[b], 1);
  }
  __syncthreads();
  for (int i = tid; i < NFINE_MAX; i += 256) {
    int c = hh[i];
    bb[i] = c ? atomicAdd(&fcur[i], c) : 0;
    hh[i] = 0;  // reuse as local cursor
  }
  __syncthreads();
  for (int i = tid; i < lim; i += 256) {
    int b = ebkt[i];
    int r = atomicAdd(&hh[b], 1);
    uint p = (uint)src[tile0 + i] | ((uint)dlow[i] << 17);
    pairs[bb[b] + r] = p;
  }
}

// one block per fine bucket: in-block scan of bucket counts, local node hist+scan
// (emits offsets), LDS-staged CSR scatter, sequential full-line flush.
__global__ __launch_bounds__(256) void k_local_scatter(const uint* __restrict__ pairs,
                                                       const int* __restrict__ fcur,
                                                       int* __restrict__ offsets,
                                                       int* __restrict__ srcs,
                                                       int n, int E, int nfine) {
  __shared__ int s_cnt[512];
  __shared__ int s_scan[512];
  __shared__ int s_stage[STAGE_CAP];
  const int b = blockIdx.x, tid = threadIdx.x;
  const int node0 = b << 9;
  const int pbase = b * PCAP;
  int c_i = (tid < nfine) ? (fcur[tid] - tid * PCAP) : 0;
  s_scan[tid] = c_i;
  __syncthreads();
  for (int d = 1; d < 256; d <<= 1) {
    int u = (tid >= d) ? s_scan[tid - d] : 0;
    __syncthreads();
    s_scan[tid] += u;
    __syncthreads();
  }
  const int ecnt = fcur[b] - pbase;
  const int ebase = s_scan[b] - ecnt;
  __syncthreads();
  s_cnt[tid] = 0;
  s_cnt[tid + 256] = 0;
  __syncthreads();
  for (int i = tid; i < ecnt; i += 256) atomicAdd(&s_cnt[pairs[pbase + i] >> 17], 1);
  __syncthreads();
  s_scan[tid] = s_cnt[tid];
  s_scan[tid + 256] = s_cnt[tid + 256];
  __syncthreads();
  for (int d = 1; d < 512; d <<= 1) {
    int v0 = (tid >= d) ? s_scan[tid - d] : 0;
    int v1 = (tid + 256 >= d) ? s_scan[tid + 256 - d] : 0;
    __syncthreads();
    s_scan[tid] += v0;
    s_scan[tid + 256] += v1;
    __syncthreads();
  }
  int e0 = s_scan[tid] - s_cnt[tid];
  int e1 = s_scan[tid + 256] - s_cnt[tid + 256];
  if (node0 + tid < n) offsets[node0 + tid] = ebase + e0;
  if (node0 + tid + 256 < n) offsets[node0 + tid + 256] = ebase + e1;
  if (b == gridDim.x - 1 && tid == 0) offsets[n] = E;
  __syncthreads();
  s_cnt[tid] = e0;
  s_cnt[tid + 256] = e1;
  __syncthreads();
  for (int i = tid; i < ecnt; i += 256) {
    uint p = pairs[pbase + i];
    int v = (int)(p >> 17);
    int s = (int)(p & 0x1FFFFu);
    int pos = atomicAdd(&s_cnt[v], 1);
    if (pos < STAGE_CAP) s_stage[pos] = s;
    else srcs[ebase + pos] = s;
  }
  __syncthreads();
  int lim = min(ecnt, STAGE_CAP);
  for (int i = tid; i < lim; i += 256) srcs[ebase + i] = s_stage[i];
}

// ---------------- mean aggregation, layer 1: int8 rows (128B), int accumulate -------
__global__ __launch_bounds__(256) void k_agg_x(const unsigned char* __restrict__ xq,
                                               const int* __restrict__ offsets,
                                               const int* __restrict__ srcs,
                                               ushort* __restrict__ mean, int n) {
  const int wid = (blockIdx.x * 256 + threadIdx.x) >> 6;
  const int lane = threadIdx.x & 63;
  const int g = lane >> 4, cl = lane & 15;
  const int node = wid * 4 + g;
  if (node >= n) return;
  const uint2* fp = reinterpret_cast<const uint2*>(xq);  // row = 16 uint2
  const int beg = offsets[node];
  const int deg = offsets[node + 1] - beg;
  int s0 = 0, s1 = 0, s2 = 0, s3 = 0, s4 = 0, s5 = 0, s6 = 0, s7 = 0;
  for (int chunk = 0; chunk < deg; chunk += 16) {
    int cnt = min(16, deg - chunk);
    int s = (cl < cnt) ? srcs[beg + chunk + cl] : 0;
    int k = 0;
    for (; k + 7 < cnt; k += 8) {
      int r0 = __shfl(s, g * 16 + k);
      int r1 = __shfl(s, g * 16 + k + 1);
      int r2 = __shfl(s, g * 16 + k + 2);
      int r3 = __shfl(s, g * 16 + k + 3);
      int r4 = __shfl(s, g * 16 + k + 4);
      int r5 = __shfl(s, g * 16 + k + 5);
      int r6 = __shfl(s, g * 16 + k + 6);
      int r7 = __shfl(s, g * 16 + k + 7);
      uint2 v0 = fp[(size_t)r0 * 16 + cl];
      uint2 v1 = fp[(size_t)r1 * 16 + cl];
      uint2 v2 = fp[(size_t)r2 * 16 + cl];
      uint2 v3 = fp[(size_t)r3 * 16 + cl];
      uint2 v4 = fp[(size_t)r4 * 16 + cl];
      uint2 v5 = fp[(size_t)r5 * 16 + cl];
      uint2 v6 = fp[(size_t)r6 * 16 + cl];
      uint2 v7 = fp[(size_t)r7 * 16 + cl];
      s0 += sb(v0.x, 0) + sb(v1.x, 0) + sb(v2.x, 0) + sb(v3.x, 0) +
            sb(v4.x, 0) + sb(v5.x, 0) + sb(v6.x, 0) + sb(v7.x, 0);
      s1 += sb(v0.x, 8) + sb(v1.x, 8) + sb(v2.x, 8) + sb(v3.x, 8) +
            sb(v4.x, 8) + sb(v5.x, 8) + sb(v6.x, 8) + sb(v7.x, 8);
      s2 += sb(v0.x, 16) + sb(v1.x, 16) + sb(v2.x, 16) + sb(v3.x, 16) +
            sb(v4.x, 16) + sb(v5.x, 16) + sb(v6.x, 16) + sb(v7.x, 16);
      s3 += sb(v0.x, 24) + sb(v1.x, 24) + sb(v2.x, 24) + sb(v3.x, 24) +
            sb(v4.x, 24) + sb(v5.x, 24) + sb(v6.x, 24) + sb(v7.x, 24);
      s4 += sb(v0.y, 0) + sb(v1.y, 0) + sb(v2.y, 0) + sb(v3.y, 0) +
            sb(v4.y, 0) + sb(v5.y, 0) + sb(v6.y, 0) + sb(v7.y, 0);
      s5 += sb(v0.y, 8) + sb(v1.y, 8) + sb(v2.y, 8) + sb(v3.y, 8) +
            sb(v4.y, 8) + sb(v5.y, 8) + sb(v6.y, 8) + sb(v7.y, 8);
      s6 += sb(v0.y, 16) + sb(v1.y, 16) + sb(v2.y, 16) + sb(v3.y, 16) +
            sb(v4.y, 16) + sb(v5.y, 16) + sb(v6.y, 16) + sb(v7.y, 16);
      s7 += sb(v0.y, 24) + sb(v1.y, 24) + sb(v2.y, 24) + sb(v3.y, 24) +
            sb(v4.y, 24) + sb(v5.y, 24) + sb(v6.y, 24) + sb(v7.y, 24);
    }
    for (; k < cnt; ++k) {
      int r0 = __shfl(s, g * 16 + k);
      uint2 v0 = fp[(size_t)r0 * 16 + cl];
      s0 += sb(v0.x, 0); s1 += sb(v0.x, 8);
      s2 += sb(v0.x, 16); s3 += sb(v0.x, 24);
      s4 += sb(v0.y, 0); s5 += sb(v0.y, 8);
      s6 += sb(v0.y, 16); s7 += sb(v0.y, 24);
    }
  }
  float inv = deg > 0 ? 1.f / (QSCALE * (float)deg) : 0.f;
  uint4 o;
  o.x = (uint)f2bf((float)s0 * inv) | ((uint)f2bf((float)s1 * inv) << 16);
  o.y = (uint)f2bf((float)s2 * inv) | ((uint)f2bf((float)s3 * inv) << 16);
  o.z = (uint)f2bf((float)s4 * inv) | ((uint)f2bf((float)s5 * inv) << 16);
  o.w = (uint)f2bf((float)s6 * inv) | ((uint)f2bf((float)s7 * inv) << 16);
  reinterpret_cast<uint4*>(mean)[(size_t)node * 16 + cl] = o;
}

// ---------------- fused layer1 GEMM + BOTH layer2 GEMMs (no h writeback) ------------
__global__ __launch_bounds__(256, 4) void k_mfma1p(const ushort* __restrict__ meanb,
                                                   const ushort* __restrict__ rootb,
                                                   const ushort* __restrict__ Wp,
                                                   const float* __restrict__ b,
                                                   const ushort* __restrict__ Wp2l,
                                                   const ushort* __restrict__ Wp2r,
                                                   const float* __restrict__ b2,
                                                   ushort* __restrict__ p,
                                                   float* __restrict__ out,
                                                   float* __restrict__ bmax, int nrows) {
  __shared__ __align__(16) ushort As[64 * 256];  // 32KB: stage/h tile + p tile
  __shared__ float s_wmax[4];
  const int tid = threadIdx.x;
  const int row0 = blockIdx.x * 64;
#pragma unroll
  for (int i = 0; i < 8; ++i) {
    int c = tid + i * 256;
    int r = c >> 5;
    int c16 = c & 31;
    int grow = row0 + r;
    short8v v = {0, 0, 0, 0, 0, 0, 0, 0};
    if (grow < nrows) {
      const ushort* srcp = (c16 < 16) ? (meanb + (size_t)grow * 128 + c16 * 8)
                                      : (rootb + (size_t)grow * 128 + (c16 - 16) * 8);
      v = *reinterpret_cast<const short8v*>(srcp);
    }
    int dbyte = r * 512 + ((c16 * 16) ^ ((r & 7) << 4));
    *reinterpret_cast<short8v*>(reinterpret_cast<char*>(As) + dbyte) = v;
  }
  __syncthreads();
  const int lane = tid & 63;
  const int rbase = (tid >> 6) * 16;
  const int arow = rbase + (lane & 15);
  const int axor = (arow & 7) << 4;
  const short8v* Wp8 = reinterpret_cast<const short8v*>(Wp);
  float4v acc[8];
#pragma unroll
  for (int f = 0; f < 8; ++f) acc[f] = {0.f, 0.f, 0.f, 0.f};
#pragma unroll
  for (int ks = 0; ks < 8; ++ks) {
    int abyte = arow * 512 + ((ks * 64 + (lane >> 4) * 16) ^ axor);
    short8v a = *reinterpret_cast<const short8v*>(reinterpret_cast<const char*>(As) + abyte);
#pragma unroll
    for (int f = 0; f < 8; ++f) {
      short8v bf = Wp8[(ks * 8 + f) * 64 + lane];
      acc[f] = __builtin_amdgcn_mfma_f32_16x16x32_bf16(a, bf, acc[f], 0, 0, 0);
    }
  }
  const int col_lo = lane & 15;
  const int rq = (lane >> 4) * 4;
  __syncthreads();  // all As reads done before overwrite
  // h fragments -> LDS only (swizzled [64][256B]); NO global h store (dead)
#pragma unroll
  for (int f = 0; f < 8; ++f) {
    int col = f * 16 + col_lo;
    float bias = b[col];
#pragma unroll
    for (int r = 0; r < 4; ++r) {
      ushort hv = f2bf(fmaxf(acc[f][r] + bias, 0.f));
      int lrow = rbase + rq + r;
      int lbyte = lrow * 256 + (((col >> 3) * 16) ^ ((lrow & 7) << 4)) + (col & 7) * 2;
      *reinterpret_cast<ushort*>(reinterpret_cast<char*>(As) + lbyte) = hv;
    }
  }
  __syncthreads();
  // phase 2: p = h@Wl2 and out_root = h@Wr2 from the LDS h tile (K=128)
  const short8v* Wq8 = reinterpret_cast<const short8v*>(Wp2l);
  const short8v* Wr8 = reinterpret_cast<const short8v*>(Wp2r);
  float4v acc2[3], acc3[3];
#pragma unroll
  for (int f = 0; f < 3; ++f) { acc2[f] = {0.f, 0.f, 0.f, 0.f}; acc3[f] = {0.f, 0.f, 0.f, 0.f}; }
#pragma unroll
  for (int ks = 0; ks < 4; ++ks) {
    int abyte = arow * 256 + ((ks * 64 + (lane >> 4) * 16) ^ axor);
    short8v a = *reinterpret_cast<const short8v*>(reinterpret_cast<const char*>(As) + abyte);
#pragma unroll
    for (int f = 0; f < 3; ++f) {
      short8v bfq = Wq8[(ks * 3 + f) * 64 + lane];
      acc2[f] = __builtin_amdgcn_mfma_f32_16x16x32_bf16(a, bfq, acc2[f], 0, 0, 0);
      short8v bfr = Wr8[(ks * 3 + f) * 64 + lane];
      acc3[f] = __builtin_amdgcn_mfma_f32_16x16x32_bf16(a, bfr, acc3[f], 0, 0, 0);
    }
  }
  // p fragments -> LDS p tile (8KB at 16KB offset, swizzled [64][128B]);
  // out_root scalar stores (64B-segment coalesced)
  ushort* Ps = As + 64 * 128;  // 16KB offset in ushorts
  float mx = 0.f;
#pragma unroll
  for (int f = 0; f < 3; ++f) {
    int col = f * 16 + col_lo;
#pragma unroll
    for (int r = 0; r < 4; ++r) {
      int lrow = rbase + rq + r;
      int pbyte = lrow * 128 + (((col >> 3) * 16) ^ ((lrow & 7) << 4)) + (col & 7) * 2;
      *reinterpret_cast<ushort*>(reinterpret_cast<char*>(Ps) + pbyte) = f2bf(acc2[f][r]);
      int row = row0 + lrow;
      if (row < nrows) {
        mx = fmaxf(mx, fabsf(acc2[f][r]));
        if (col < CLSN)
          out[(size_t)row * CLSN + col] = acc3[f][r] + b2[col];
      }
    }
  }
#pragma unroll
  for (int r = 0; r < 4; ++r) {
    int lrow = rbase + rq + r;
    int col = 48 + col_lo;
    int pbyte = lrow * 128 + (((col >> 3) * 16) ^ ((lrow & 7) << 4)) + (col & 7) * 2;
    *reinterpret_cast<ushort*>(reinterpret_cast<char*>(Ps) + pbyte) = 0;
  }
  __syncthreads();
  // coalesced p write: 512 x 16B chunks
#pragma unroll
  for (int i = 0; i < 2; ++i) {
    int c = tid + i * 256;
    int r = c >> 3, c8 = c & 7;
    int grow = row0 + r;
    int lbyte = r * 128 + ((c8 * 16) ^ ((r & 7) << 4));
    short8v v = *reinterpret_cast<const short8v*>(reinterpret_cast<const char*>(Ps) + lbyte);
    if (grow < nrows)
      *reinterpret_cast<short8v*>(p + (size_t)grow * 64 + c8 * 8) = v;
  }
#pragma unroll
  for (int d = 32; d; d >>= 1) mx = fmaxf(mx, __shfl_xor(mx, d));
  if (lane == 0) s_wmax[tid >> 6] = mx;
  __syncthreads();
  if (tid == 0)
    bmax[blockIdx.x] = fmaxf(fmaxf(s_wmax[0], s_wmax[1]), fmaxf(s_wmax[2], s_wmax[3]));
}

// ---------------- quantize p -> int8; per-wave inline reduction of bmax -------------
__global__ __launch_bounds__(256) void k_quant_p(const ushort* __restrict__ p,
                                                 const float* __restrict__ bmax,
                                                 unsigned char* __restrict__ pq,
                                                 int nelem4, int nb) {
  const int lane = threadIdx.x & 63;
  float ma = wave_max_bmax(bmax, nb, lane);  // all lanes active
  float qs = ma > 0.f ? 127.f / ma : 0.f;
  int i = blockIdx.x * 256 + threadIdx.x;
  if (i >= nelem4) return;
  uint2 v = reinterpret_cast<const uint2*>(p)[i];
  uchar4 q;
  q.x = q8s(bfLo(v.x), qs);
  q.y = q8s(bfHi(v.x), qs);
  q.z = q8s(bfLo(v.y), qs);
  q.w = q8s(bfHi(v.y), qs);
  reinterpret_cast<uchar4*>(pq)[i] = q;
}

// ---------------- layer2 aggregate + accumulate: out += mean(pq) --------------------
__global__ __launch_bounds__(256) void k_agg_add(const unsigned char* __restrict__ pq,
                                                 const int* __restrict__ offsets,
                                                 const int* __restrict__ srcs,
                                                 const float* __restrict__ bmax,
                                                 float* __restrict__ out, int n, int nb) {
  const int wid = (blockIdx.x * 256 + threadIdx.x) >> 6;
  const int lane = threadIdx.x & 63;
  float ma = wave_max_bmax(bmax, nb, lane);  // all lanes active before early return
  const int g = lane >> 3, cl = lane & 7;
  const int node = wid * 8 + g;
  if (node >= n) return;
  const uint2* pp = reinterpret_cast<const uint2*>(pq);  // row = 8 uint2 (64B)
  const int beg = offsets[node];
  const int deg = offsets[node + 1] - beg;
  int s0 = 0, s1 = 0, s2 = 0, s3 = 0, s4 = 0, s5 = 0, s6 = 0, s7 = 0;
  for (int chunk = 0; chunk < deg; chunk += 8) {
    int cnt = min(8, deg - chunk);
    int s = (cl < cnt) ? srcs[beg + chunk + cl] : 0;
    int k = 0;
    for (; k + 7 < cnt; k += 8) {
      int r0 = __shfl(s, g * 8 + k);
      int r1 = __shfl(s, g * 8 + k + 1);
      int r2 = __shfl(s, g * 8 + k + 2);
      int r3 = __shfl(s, g * 8 + k + 3);
      int r4 = __shfl(s, g * 8 + k + 4);
      int r5 = __shfl(s, g * 8 + k + 5);
      int r6 = __shfl(s, g * 8 + k + 6);
      int r7 = __shfl(s, g * 8 + k + 7);
      uint2 v0 = pp[(size_t)r0 * 8 + cl];
      uint2 v1 = pp[(size_t)r1 * 8 + cl];
      uint2 v2 = pp[(size_t)r2 * 8 + cl];
      uint2 v3 = pp[(size_t)r3 * 8 + cl];
      uint2 v4 = pp[(size_t)r4 * 8 + cl];
      uint2 v5 = pp[(size_t)r5 * 8 + cl];
      uint2 v6 = pp[(size_t)r6 * 8 + cl];
      uint2 v7 = pp[(size_t)r7 * 8 + cl];
      s0 += sb(v0.x, 0) + sb(v1.x, 0) + sb(v2.x, 0) + sb(v3.x, 0) +
            sb(v4.x, 0) + sb(v5.x, 0) + sb(v6.x, 0) + sb(v7.x, 0);
      s1 += sb(v0.x, 8) + sb(v1.x, 8) + sb(v2.x, 8) + sb(v3.x, 8) +
            sb(v4.x, 8) + sb(v5.x, 8) + sb(v6.x, 8) + sb(v7.x, 8);
      s2 += sb(v0.x, 16) + sb(v1.x, 16) + sb(v2.x, 16) + sb(v3.x, 16) +
            sb(v4.x, 16) + sb(v5.x, 16) + sb(v6.x, 16) + sb(v7.x, 16);
      s3 += sb(v0.x, 24) + sb(v1.x, 24) + sb(v2.x, 24) + sb(v3.x, 24) +
            sb(v4.x, 24) + sb(v5.x, 24) + sb(v6.x, 24) + sb(v7.x, 24);
      s4 += sb(v0.y, 0) + sb(v1.y, 0) + sb(v2.y, 0) + sb(v3.y, 0) +
            sb(v4.y, 0) + sb(v5.y, 0) + sb(v6.y, 0) + sb(v7.y, 0);
      s5 += sb(v0.y, 8) + sb(v1.y, 8) + sb(v2.y, 8) + sb(v3.y, 8) +
            sb(v4.y, 8) + sb(v5.y, 8) + sb(v6.y, 8) + sb(v7.y, 8);
      s6 += sb(v0.y, 16) + sb(v1.y, 16) + sb(v2.y, 16) + sb(v3.y, 16) +
            sb(v4.y, 16) + sb(v5.y, 16) + sb(v6.y, 16) + sb(v7.y, 16);
      s7 += sb(v0.y, 24) + sb(v1.y, 24) + sb(v2.y, 24) + sb(v3.y, 24) +
            sb(v4.y, 24) + sb(v5.y, 24) + sb(v6.y, 24) + sb(v7.y, 24);
    }
    for (; k < cnt; ++k) {
      int r0 = __shfl(s, g * 8 + k);
      uint2 v0 = pp[(size_t)r0 * 8 + cl];
      s0 += sb(v0.x, 0); s1 += sb(v0.x, 8);
      s2 += sb(v0.x, 16); s3 += sb(v0.x, 24);
      s4 += sb(v0.y, 0); s5 += sb(v0.y, 8);
      s6 += sb(v0.y, 16); s7 += sb(v0.y, 24);
    }
  }
  if (cl < 5) {  // cols cl*8 .. cl*8+7 are real (40 cols total)
    float inv = deg > 0 ? ma / (127.f * (float)deg) : 0.f;
    float* op = out + (size_t)node * CLSN + cl * 8;
    float4 a0 = *reinterpret_cast<float4*>(op);
    float4 a1 = *reinterpret_cast<float4*>(op + 4);
    a0.x += (float)s0 * inv; a0.y += (float)s1 * inv;
    a0.z += (float)s2 * inv; a0.w += (float)s3 * inv;
    a1.x += (float)s4 * inv; a1.y += (float)s5 * inv;
    a1.z += (float)s6 * inv; a1.w += (float)s7 * inv;
    *reinterpret_cast<float4*>(op) = a0;
    *reinterpret_cast<float4*>(op + 4) = a1;
  }
}

extern "C" void kernel_launch(void* const* d_in, const int* in_sizes, int n_in,
                              void* d_out, int out_size, void* d_ws, size_t ws_size,
                              hipStream_t stream) {
  const float* x = (const float*)d_in[0];
  const int* ei = (const int*)d_in[1];
  const float* Wl1 = (const float*)d_in[2];
  const float* Wr1 = (const float*)d_in[3];
  const float* b1 = (const float*)d_in[4];
  const float* Wl2 = (const float*)d_in[5];
  const float* Wr2 = (const float*)d_in[6];
  const float* b2 = (const float*)d_in[7];
  float* out = (float*)d_out;

  const int n = in_sizes[0] / F;
  const int E = in_sizes[1] / 2;
  const int* src = ei;
  const int* dst = ei + E;

  const int nfine = (n + 511) >> 9;  // 196
  const int ngemm = (n + 63) / 64;   // 1563

  size_t off = 0;
  auto alloc = [&](size_t bytes) {
    size_t cur = off;
    off = (off + bytes + 255) & ~(size_t)255;
    return cur;
  };
  char* w = (char*)d_ws;
  int* offsets = (int*)(w + alloc((size_t)(n + 1) * 4));
  int* srcs = (int*)(w + alloc((size_t)E * 4));
  int* fcur = (int*)(w + alloc(NFINE_MAX * 4));
  float* bmax = (float*)(w + alloc((size_t)(ngemm + 8) * 4));
  ushort* xb = (ushort*)(w + alloc((size_t)n * F * 2));
  ushort* hb = (ushort*)(w + alloc((size_t)n * F * 2));
  ushort* meanb = (ushort*)(w + alloc((size_t)n * F * 2));
  ushort* Wp1 = (ushort*)(w + alloc(32768 * 2));
  ushort* Wp2l = (ushort*)(w + alloc(6144 * 2));
  ushort* Wp2r = (ushort*)(w + alloc(6144 * 2));
  (void)ws_size;
  // aliases (lifetime-disjoint, race-free):
  //   pairs (CSR build) -> meanb region (dead before agg_x writes mean)
  //   xq8 int8 [n][128] -> hb FIRST half (read by agg_x, dead before mfma1p)
  //   p64 bf16 [n][64]  -> hb SECOND half (written by mfma1p; NO overlap with meanb)
  //   pq8 int8 [n][64]  -> meanb second half (meanb dead after mfma1p staging)
  uint* pairs = (uint*)meanb;
  unsigned char* xq8 = (unsigned char*)hb;
  ushort* p64 = hb + (size_t)n * 64;
  unsigned char* pq8 = (unsigned char*)(meanb + (size_t)n * 64);

  const int castBlocks = (n * 32 + 255) / 256;

  // fused prep: cast x, pack W1/W2, init fcur
  k_prep<<<castBlocks + 23, 256, 0, stream>>>(x, xb, xq8, Wl1, Wr1, Wp1, Wl2, Wr2,
                                              Wp2l, Wp2r, fcur, n * 32, castBlocks,
                                              nfine);

  // binned CSR build
  k_partition<<<(E + TILE - 1) / TILE, 256, 0, stream>>>(src, dst, fcur, pairs, E);
  k_local_scatter<<<nfine, 256, 0, stream>>>(pairs, fcur, offsets, srcs, n, E, nfine);

  // layer 1: mean(x) via int8 gather -> fused h-GEMM + p-projection + root-GEMM
  k_agg_x<<<(n + 15) / 16, 256, 0, stream>>>(xq8, offsets, srcs, meanb, n);
  k_mfma1p<<<ngemm, 256, 0, stream>>>(meanb, xb, Wp1, b1, Wp2l, Wp2r, b2, p64,
                                      out, bmax, n);

  // layer 2 tail: quantize p (inline scale); gather-aggregate and accumulate into out
  k_quant_p<<<(n * 16 + 255) / 256, 256, 0, stream>>>(p64, bmax, pq8, n * 16, ngemm);
  k_agg_add<<<(n + 31) / 32, 256, 0, stream>>>(pq8, offsets, srcs, bmax, out, n, ngemm);
}

// Round 22
// 172.545 us; speedup vs baseline: 1.0997x; 1.0997x over previous
//
#include <hip/hip_runtime.h>

#define F 128
#define CLSN 40
#define NFINE_MAX 256
#define PCAP 10240
#define TILE 4096
#define STAGE_CAP 10240
#define QSCALE 22.0f

typedef __attribute__((ext_vector_type(8))) short short8v;
typedef __attribute__((ext_vector_type(4))) float float4v;

static __device__ inline ushort f2bf(float f) {
  uint u = __float_as_uint(f);
  uint r = (u + 0x7FFFu + ((u >> 16) & 1u)) >> 16;
  return (ushort)r;
}
static __device__ inline float bfLo(uint u) { return __uint_as_float(u << 16); }
static __device__ inline float bfHi(uint u) { return __uint_as_float(u & 0xFFFF0000u); }
static __device__ inline int sb(uint v, int sh) { return (int)(signed char)(v >> sh); }
static __device__ inline unsigned char q8(float f) {
  float t = rintf(f * QSCALE);
  t = fminf(fmaxf(t, -127.f), 127.f);
  return (unsigned char)(signed char)(int)t;
}
static __device__ inline unsigned char q8s(float f, float qs) {
  float t = rintf(f * qs);
  t = fminf(fmaxf(t, -127.f), 127.f);
  return (unsigned char)(signed char)(int)t;
}

// ---------------- fused prep: cast x (bf16 + int8), pack weights, init cursors -------
__global__ __launch_bounds__(256) void k_prep(const float* __restrict__ x,
                                              ushort* __restrict__ xb,
                                              unsigned char* __restrict__ xq,
                                              const float* __restrict__ Wl1,
                                              const float* __restrict__ Wr1,
                                              ushort* __restrict__ Wp1,
                                              const float* __restrict__ Wl2,
                                              const float* __restrict__ Wr2,
                                              ushort* __restrict__ Wpl,
                                              ushort* __restrict__ Wpr,
                                              int* __restrict__ fcur,
                                              int nelem4, int castBlocks, int nfine) {
  const int blk = blockIdx.x;
  if (blk < castBlocks) {
    int i = blk * 256 + threadIdx.x;
    if (i < nelem4) {
      float4 v = reinterpret_cast<const float4*>(x)[i];
      ushort4 o;
      o.x = f2bf(v.x); o.y = f2bf(v.y); o.z = f2bf(v.z); o.w = f2bf(v.w);
      reinterpret_cast<ushort4*>(xb)[i] = o;
      uchar4 q;
      q.x = q8(v.x); q.y = q8(v.y); q.z = q8(v.z); q.w = q8(v.w);
      reinterpret_cast<uchar4*>(xq)[i] = q;
    }
  } else if (blk < castBlocks + 16) {
    int t = (blk - castBlocks) * 256 + threadIdx.x;
    int lane = t & 63, f = (t >> 6) & 7, ks = t >> 9;
    int col = f * 16 + (lane & 15);
    int k0 = ks * 32 + (lane >> 4) * 8;
#pragma unroll
    for (int j = 0; j < 8; ++j) {
      int k = k0 + j;
      float w = (k < 128) ? Wl1[k * 128 + col] : Wr1[(k - 128) * 128 + col];
      Wp1[t * 8 + j] = f2bf(w);
    }
  } else if (blk < castBlocks + 22) {
    int t = (blk - castBlocks - 16) * 256 + threadIdx.x;
    const float* W = (t < 768) ? Wl2 : Wr2;
    ushort* Wp = (t < 768) ? Wpl : Wpr;
    int tt = (t < 768) ? t : t - 768;
    int lane = tt & 63, rem = tt >> 6;
    int f = rem % 3, ks = rem / 3;
    int col = f * 16 + (lane & 15);
    int k0 = ks * 32 + (lane >> 4) * 8;
#pragma unroll
    for (int j = 0; j < 8; ++j) {
      int k = k0 + j;
      float w = (col < CLSN) ? W[k * CLSN + col] : 0.f;
      Wp[tt * 8 + j] = f2bf(w);
    }
  } else {
    int i = threadIdx.x;
    if (i < nfine) fcur[i] = i * PCAP;
  }
}

// ---------------- one-pass tiled radix partition into fine buckets ----------------
__global__ __launch_bounds__(256) void k_partition(const int* __restrict__ src,
                                                   const int* __restrict__ dst,
                                                   int* __restrict__ fcur,
                                                   uint* __restrict__ pairs, int E) {
  __shared__ int hh[NFINE_MAX];
  __shared__ int bb[NFINE_MAX];
  __shared__ unsigned char ebkt[TILE];
  __shared__ ushort dlow[TILE];
  const int tid = threadIdx.x;
  const int tile0 = blockIdx.x * TILE;
  const int lim = min(TILE, E - tile0);
  for (int i = tid; i < NFINE_MAX; i += 256) hh[i] = 0;
  __syncthreads();
  for (int i = tid; i < lim; i += 256) {
    int d = dst[tile0 + i];
    int b = d >> 9;
    ebkt[i] = (unsigned char)b;
    dlow[i] = (ushort)(d & 511);
    atomicAdd(&hh[b], 1);
  }
  __syncthreads();
  for (int i = tid; i < NFINE_MAX; i += 256) {
    int c = hh[i];
    bb[i] = c ? atomicAdd(&fcur[i], c) : 0;
    hh[i] = 0;  // reuse as local cursor
  }
  __syncthreads();
  for (int i = tid; i < lim; i += 256) {
    int b = ebkt[i];
    int r = atomicAdd(&hh[b], 1);
    uint p = (uint)src[tile0 + i] | ((uint)dlow[i] << 17);
    pairs[bb[b] + r] = p;
  }
}

// one block per fine bucket: in-block scan of bucket counts, local node hist+scan
// (emits offsets), LDS-staged CSR scatter, sequential full-line flush.
__global__ __launch_bounds__(256) void k_local_scatter(const uint* __restrict__ pairs,
                                                       const int* __restrict__ fcur,
                                                       int* __restrict__ offsets,
                                                       int* __restrict__ srcs,
                                                       int n, int E, int nfine) {
  __shared__ int s_cnt[512];
  __shared__ int s_scan[512];
  __shared__ int s_stage[STAGE_CAP];
  const int b = blockIdx.x, tid = threadIdx.x;
  const int node0 = b << 9;
  const int pbase = b * PCAP;
  int c_i = (tid < nfine) ? (fcur[tid] - tid * PCAP) : 0;
  s_scan[tid] = c_i;
  __syncthreads();
  for (int d = 1; d < 256; d <<= 1) {
    int u = (tid >= d) ? s_scan[tid - d] : 0;
    __syncthreads();
    s_scan[tid] += u;
    __syncthreads();
  }
  const int ecnt = fcur[b] - pbase;
  const int ebase = s_scan[b] - ecnt;
  __syncthreads();
  s_cnt[tid] = 0;
  s_cnt[tid + 256] = 0;
  __syncthreads();
  for (int i = tid; i < ecnt; i += 256) atomicAdd(&s_cnt[pairs[pbase + i] >> 17], 1);
  __syncthreads();
  s_scan[tid] = s_cnt[tid];
  s_scan[tid + 256] = s_cnt[tid + 256];
  __syncthreads();
  for (int d = 1; d < 512; d <<= 1) {
    int v0 = (tid >= d) ? s_scan[tid - d] : 0;
    int v1 = (tid + 256 >= d) ? s_scan[tid + 256 - d] : 0;
    __syncthreads();
    s_scan[tid] += v0;
    s_scan[tid + 256] += v1;
    __syncthreads();
  }
  int e0 = s_scan[tid] - s_cnt[tid];
  int e1 = s_scan[tid + 256] - s_cnt[tid + 256];
  if (node0 + tid < n) offsets[node0 + tid] = ebase + e0;
  if (node0 + tid + 256 < n) offsets[node0 + tid + 256] = ebase + e1;
  if (b == gridDim.x - 1 && tid == 0) offsets[n] = E;
  __syncthreads();
  s_cnt[tid] = e0;
  s_cnt[tid + 256] = e1;
  __syncthreads();
  for (int i = tid; i < ecnt; i += 256) {
    uint p = pairs[pbase + i];
    int v = (int)(p >> 17);
    int s = (int)(p & 0x1FFFFu);
    int pos = atomicAdd(&s_cnt[v], 1);
    if (pos < STAGE_CAP) s_stage[pos] = s;
    else srcs[ebase + pos] = s;
  }
  __syncthreads();
  int lim = min(ecnt, STAGE_CAP);
  for (int i = tid; i < lim; i += 256) srcs[ebase + i] = s_stage[i];
}

// ---------------- mean aggregation, layer 1: int8 rows (128B), int accumulate -------
__global__ __launch_bounds__(256) void k_agg_x(const unsigned char* __restrict__ xq,
                                               const int* __restrict__ offsets,
                                               const int* __restrict__ srcs,
                                               ushort* __restrict__ mean, int n) {
  const int wid = (blockIdx.x * 256 + threadIdx.x) >> 6;
  const int lane = threadIdx.x & 63;
  const int g = lane >> 4, cl = lane & 15;
  const int node = wid * 4 + g;
  if (node >= n) return;
  const uint2* fp = reinterpret_cast<const uint2*>(xq);  // row = 16 uint2
  const int beg = offsets[node];
  const int deg = offsets[node + 1] - beg;
  int s0 = 0, s1 = 0, s2 = 0, s3 = 0, s4 = 0, s5 = 0, s6 = 0, s7 = 0;
  for (int chunk = 0; chunk < deg; chunk += 16) {
    int cnt = min(16, deg - chunk);
    int s = (cl < cnt) ? srcs[beg + chunk + cl] : 0;
    int k = 0;
    for (; k + 7 < cnt; k += 8) {
      int r0 = __shfl(s, g * 16 + k);
      int r1 = __shfl(s, g * 16 + k + 1);
      int r2 = __shfl(s, g * 16 + k + 2);
      int r3 = __shfl(s, g * 16 + k + 3);
      int r4 = __shfl(s, g * 16 + k + 4);
      int r5 = __shfl(s, g * 16 + k + 5);
      int r6 = __shfl(s, g * 16 + k + 6);
      int r7 = __shfl(s, g * 16 + k + 7);
      uint2 v0 = fp[(size_t)r0 * 16 + cl];
      uint2 v1 = fp[(size_t)r1 * 16 + cl];
      uint2 v2 = fp[(size_t)r2 * 16 + cl];
      uint2 v3 = fp[(size_t)r3 * 16 + cl];
      uint2 v4 = fp[(size_t)r4 * 16 + cl];
      uint2 v5 = fp[(size_t)r5 * 16 + cl];
      uint2 v6 = fp[(size_t)r6 * 16 + cl];
      uint2 v7 = fp[(size_t)r7 * 16 + cl];
      s0 += sb(v0.x, 0) + sb(v1.x, 0) + sb(v2.x, 0) + sb(v3.x, 0) +
            sb(v4.x, 0) + sb(v5.x, 0) + sb(v6.x, 0) + sb(v7.x, 0);
      s1 += sb(v0.x, 8) + sb(v1.x, 8) + sb(v2.x, 8) + sb(v3.x, 8) +
            sb(v4.x, 8) + sb(v5.x, 8) + sb(v6.x, 8) + sb(v7.x, 8);
      s2 += sb(v0.x, 16) + sb(v1.x, 16) + sb(v2.x, 16) + sb(v3.x, 16) +
            sb(v4.x, 16) + sb(v5.x, 16) + sb(v6.x, 16) + sb(v7.x, 16);
      s3 += sb(v0.x, 24) + sb(v1.x, 24) + sb(v2.x, 24) + sb(v3.x, 24) +
            sb(v4.x, 24) + sb(v5.x, 24) + sb(v6.x, 24) + sb(v7.x, 24);
      s4 += sb(v0.y, 0) + sb(v1.y, 0) + sb(v2.y, 0) + sb(v3.y, 0) +
            sb(v4.y, 0) + sb(v5.y, 0) + sb(v6.y, 0) + sb(v7.y, 0);
      s5 += sb(v0.y, 8) + sb(v1.y, 8) + sb(v2.y, 8) + sb(v3.y, 8) +
            sb(v4.y, 8) + sb(v5.y, 8) + sb(v6.y, 8) + sb(v7.y, 8);
      s6 += sb(v0.y, 16) + sb(v1.y, 16) + sb(v2.y, 16) + sb(v3.y, 16) +
            sb(v4.y, 16) + sb(v5.y, 16) + sb(v6.y, 16) + sb(v7.y, 16);
      s7 += sb(v0.y, 24) + sb(v1.y, 24) + sb(v2.y, 24) + sb(v3.y, 24) +
            sb(v4.y, 24) + sb(v5.y, 24) + sb(v6.y, 24) + sb(v7.y, 24);
    }
    for (; k < cnt; ++k) {
      int r0 = __shfl(s, g * 16 + k);
      uint2 v0 = fp[(size_t)r0 * 16 + cl];
      s0 += sb(v0.x, 0); s1 += sb(v0.x, 8);
      s2 += sb(v0.x, 16); s3 += sb(v0.x, 24);
      s4 += sb(v0.y, 0); s5 += sb(v0.y, 8);
      s6 += sb(v0.y, 16); s7 += sb(v0.y, 24);
    }
  }
  float inv = deg > 0 ? 1.f / (QSCALE * (float)deg) : 0.f;
  uint4 o;
  o.x = (uint)f2bf((float)s0 * inv) | ((uint)f2bf((float)s1 * inv) << 16);
  o.y = (uint)f2bf((float)s2 * inv) | ((uint)f2bf((float)s3 * inv) << 16);
  o.z = (uint)f2bf((float)s4 * inv) | ((uint)f2bf((float)s5 * inv) << 16);
  o.w = (uint)f2bf((float)s6 * inv) | ((uint)f2bf((float)s7 * inv) << 16);
  reinterpret_cast<uint4*>(mean)[(size_t)node * 16 + cl] = o;
}

// ---------------- fused layer1 GEMM + BOTH layer2 GEMMs (no h writeback) ------------
__global__ __launch_bounds__(256) void k_mfma1p(const ushort* __restrict__ meanb,
                                                const ushort* __restrict__ rootb,
                                                const ushort* __restrict__ Wp,
                                                const float* __restrict__ b,
                                                const ushort* __restrict__ Wp2l,
                                                const ushort* __restrict__ Wp2r,
                                                const float* __restrict__ b2,
                                                ushort* __restrict__ p,
                                                float* __restrict__ out,
                                                float* __restrict__ bmax, int nrows) {
  __shared__ __align__(16) ushort As[64 * 256];  // 32KB: stage/h tile + p tile
  __shared__ float s_wmax[4];
  const int tid = threadIdx.x;
  const int row0 = blockIdx.x * 64;
#pragma unroll
  for (int i = 0; i < 8; ++i) {
    int c = tid + i * 256;
    int r = c >> 5;
    int c16 = c & 31;
    int grow = row0 + r;
    short8v v = {0, 0, 0, 0, 0, 0, 0, 0};
    if (grow < nrows) {
      const ushort* srcp = (c16 < 16) ? (meanb + (size_t)grow * 128 + c16 * 8)
                                      : (rootb + (size_t)grow * 128 + (c16 - 16) * 8);
      v = *reinterpret_cast<const short8v*>(srcp);
    }
    int dbyte = r * 512 + ((c16 * 16) ^ ((r & 7) << 4));
    *reinterpret_cast<short8v*>(reinterpret_cast<char*>(As) + dbyte) = v;
  }
  __syncthreads();
  const int lane = tid & 63;
  const int rbase = (tid >> 6) * 16;
  const int arow = rbase + (lane & 15);
  const int axor = (arow & 7) << 4;
  const short8v* Wp8 = reinterpret_cast<const short8v*>(Wp);
  float4v acc[8];
#pragma unroll
  for (int f = 0; f < 8; ++f) acc[f] = {0.f, 0.f, 0.f, 0.f};
#pragma unroll
  for (int ks = 0; ks < 8; ++ks) {
    int abyte = arow * 512 + ((ks * 64 + (lane >> 4) * 16) ^ axor);
    short8v a = *reinterpret_cast<const short8v*>(reinterpret_cast<const char*>(As) + abyte);
#pragma unroll
    for (int f = 0; f < 8; ++f) {
      short8v bf = Wp8[(ks * 8 + f) * 64 + lane];
      acc[f] = __builtin_amdgcn_mfma_f32_16x16x32_bf16(a, bf, acc[f], 0, 0, 0);
    }
  }
  const int col_lo = lane & 15;
  const int rq = (lane >> 4) * 4;
  __syncthreads();  // all As reads done before overwrite
  // h fragments -> LDS only (swizzled [64][256B]); NO global h store (dead)
#pragma unroll
  for (int f = 0; f < 8; ++f) {
    int col = f * 16 + col_lo;
    float bias = b[col];
#pragma unroll
    for (int r = 0; r < 4; ++r) {
      ushort hv = f2bf(fmaxf(acc[f][r] + bias, 0.f));
      int lrow = rbase + rq + r;
      int lbyte = lrow * 256 + (((col >> 3) * 16) ^ ((lrow & 7) << 4)) + (col & 7) * 2;
      *reinterpret_cast<ushort*>(reinterpret_cast<char*>(As) + lbyte) = hv;
    }
  }
  __syncthreads();
  // phase 2: p = h@Wl2 and out_root = h@Wr2 from the LDS h tile (K=128)
  const short8v* Wq8 = reinterpret_cast<const short8v*>(Wp2l);
  const short8v* Wr8 = reinterpret_cast<const short8v*>(Wp2r);
  float4v acc2[3], acc3[3];
#pragma unroll
  for (int f = 0; f < 3; ++f) { acc2[f] = {0.f, 0.f, 0.f, 0.f}; acc3[f] = {0.f, 0.f, 0.f, 0.f}; }
#pragma unroll
  for (int ks = 0; ks < 4; ++ks) {
    int abyte = arow * 256 + ((ks * 64 + (lane >> 4) * 16) ^ axor);
    short8v a = *reinterpret_cast<const short8v*>(reinterpret_cast<const char*>(As) + abyte);
#pragma unroll
    for (int f = 0; f < 3; ++f) {
      short8v bfq = Wq8[(ks * 3 + f) * 64 + lane];
      acc2[f] = __builtin_amdgcn_mfma_f32_16x16x32_bf16(a, bfq, acc2[f], 0, 0, 0);
      short8v bfr = Wr8[(ks * 3 + f) * 64 + lane];
      acc3[f] = __builtin_amdgcn_mfma_f32_16x16x32_bf16(a, bfr, acc3[f], 0, 0, 0);
    }
  }
  // p fragments -> LDS p tile (8KB at 16KB offset, swizzled [64][128B]);
  // out_root scalar stores (64B-segment coalesced)
  ushort* Ps = As + 64 * 128;  // 16KB offset in ushorts
  float mx = 0.f;
#pragma unroll
  for (int f = 0; f < 3; ++f) {
    int col = f * 16 + col_lo;
#pragma unroll
    for (int r = 0; r < 4; ++r) {
      int lrow = rbase + rq + r;
      int pbyte = lrow * 128 + (((col >> 3) * 16) ^ ((lrow & 7) << 4)) + (col & 7) * 2;
      *reinterpret_cast<ushort*>(reinterpret_cast<char*>(Ps) + pbyte) = f2bf(acc2[f][r]);
      int row = row0 + lrow;
      if (row < nrows) {
        mx = fmaxf(mx, fabsf(acc2[f][r]));
        if (col < CLSN)
          out[(size_t)row * CLSN + col] = acc3[f][r] + b2[col];
      }
    }
  }
#pragma unroll
  for (int r = 0; r < 4; ++r) {
    int lrow = rbase + rq + r;
    int col = 48 + col_lo;
    int pbyte = lrow * 128 + (((col >> 3) * 16) ^ ((lrow & 7) << 4)) + (col & 7) * 2;
    *reinterpret_cast<ushort*>(reinterpret_cast<char*>(Ps) + pbyte) = 0;
  }
  __syncthreads();
  // coalesced p write: 512 x 16B chunks
#pragma unroll
  for (int i = 0; i < 2; ++i) {
    int c = tid + i * 256;
    int r = c >> 3, c8 = c & 7;
    int grow = row0 + r;
    int lbyte = r * 128 + ((c8 * 16) ^ ((r & 7) << 4));
    short8v v = *reinterpret_cast<const short8v*>(reinterpret_cast<const char*>(Ps) + lbyte);
    if (grow < nrows)
      *reinterpret_cast<short8v*>(p + (size_t)grow * 64 + c8 * 8) = v;
  }
#pragma unroll
  for (int d = 32; d; d >>= 1) mx = fmaxf(mx, __shfl_xor(mx, d));
  if (lane == 0) s_wmax[tid >> 6] = mx;
  __syncthreads();
  if (tid == 0)
    bmax[blockIdx.x] = fmaxf(fmaxf(s_wmax[0], s_wmax[1]), fmaxf(s_wmax[2], s_wmax[3]));
}

// ---------------- reduce per-block maxima -> single scale ---------------------------
__global__ __launch_bounds__(256) void k_scl(const float* __restrict__ bmax,
                                             float* __restrict__ scl, int nb) {
  __shared__ float s_w[4];
  float mx = 0.f;
  for (int i = threadIdx.x; i < nb; i += 256) mx = fmaxf(mx, bmax[i]);
#pragma unroll
  for (int d = 32; d; d >>= 1) mx = fmaxf(mx, __shfl_xor(mx, d));
  if ((threadIdx.x & 63) == 0) s_w[threadIdx.x >> 6] = mx;
  __syncthreads();
  if (threadIdx.x == 0)
    *scl = fmaxf(fmaxf(s_w[0], s_w[1]), fmaxf(s_w[2], s_w[3]));
}

// ---------------- quantize p -> int8 using dynamic per-tensor scale -----------------
__global__ __launch_bounds__(256) void k_quant_p(const ushort* __restrict__ p,
                                                 const float* __restrict__ scl,
                                                 unsigned char* __restrict__ pq, int nelem4) {
  int i = blockIdx.x * 256 + threadIdx.x;
  if (i >= nelem4) return;
  float ma = *scl;
  float qs = ma > 0.f ? 127.f / ma : 0.f;
  uint2 v = reinterpret_cast<const uint2*>(p)[i];
  uchar4 q;
  q.x = q8s(bfLo(v.x), qs);
  q.y = q8s(bfHi(v.x), qs);
  q.z = q8s(bfLo(v.y), qs);
  q.w = q8s(bfHi(v.y), qs);
  reinterpret_cast<uchar4*>(pq)[i] = q;
}

// ---------------- layer2 aggregate + accumulate: out += mean(pq) --------------------
__global__ __launch_bounds__(256) void k_agg_add(const unsigned char* __restrict__ pq,
                                                 const int* __restrict__ offsets,
                                                 const int* __restrict__ srcs,
                                                 const float* __restrict__ scl,
                                                 float* __restrict__ out, int n) {
  const int wid = (blockIdx.x * 256 + threadIdx.x) >> 6;
  const int lane = threadIdx.x & 63;
  const int g = lane >> 3, cl = lane & 7;
  const int node = wid * 8 + g;
  if (node >= n) return;
  const uint2* pp = reinterpret_cast<const uint2*>(pq);  // row = 8 uint2 (64B)
  const int beg = offsets[node];
  const int deg = offsets[node + 1] - beg;
  int s0 = 0, s1 = 0, s2 = 0, s3 = 0, s4 = 0, s5 = 0, s6 = 0, s7 = 0;
  for (int chunk = 0; chunk < deg; chunk += 8) {
    int cnt = min(8, deg - chunk);
    int s = (cl < cnt) ? srcs[beg + chunk + cl] : 0;
    int k = 0;
    for (; k + 7 < cnt; k += 8) {
      int r0 = __shfl(s, g * 8 + k);
      int r1 = __shfl(s, g * 8 + k + 1);
      int r2 = __shfl(s, g * 8 + k + 2);
      int r3 = __shfl(s, g * 8 + k + 3);
      int r4 = __shfl(s, g * 8 + k + 4);
      int r5 = __shfl(s, g * 8 + k + 5);
      int r6 = __shfl(s, g * 8 + k + 6);
      int r7 = __shfl(s, g * 8 + k + 7);
      uint2 v0 = pp[(size_t)r0 * 8 + cl];
      uint2 v1 = pp[(size_t)r1 * 8 + cl];
      uint2 v2 = pp[(size_t)r2 * 8 + cl];
      uint2 v3 = pp[(size_t)r3 * 8 + cl];
      uint2 v4 = pp[(size_t)r4 * 8 + cl];
      uint2 v5 = pp[(size_t)r5 * 8 + cl];
      uint2 v6 = pp[(size_t)r6 * 8 + cl];
      uint2 v7 = pp[(size_t)r7 * 8 + cl];
      s0 += sb(v0.x, 0) + sb(v1.x, 0) + sb(v2.x, 0) + sb(v3.x, 0) +
            sb(v4.x, 0) + sb(v5.x, 0) + sb(v6.x, 0) + sb(v7.x, 0);
      s1 += sb(v0.x, 8) + sb(v1.x, 8) + sb(v2.x, 8) + sb(v3.x, 8) +
            sb(v4.x, 8) + sb(v5.x, 8) + sb(v6.x, 8) + sb(v7.x, 8);
      s2 += sb(v0.x, 16) + sb(v1.x, 16) + sb(v2.x, 16) + sb(v3.x, 16) +
            sb(v4.x, 16) + sb(v5.x, 16) + sb(v6.x, 16) + sb(v7.x, 16);
      s3 += sb(v0.x, 24) + sb(v1.x, 24) + sb(v2.x, 24) + sb(v3.x, 24) +
            sb(v4.x, 24) + sb(v5.x, 24) + sb(v6.x, 24) + sb(v7.x, 24);
      s4 += sb(v0.y, 0) + sb(v1.y, 0) + sb(v2.y, 0) + sb(v3.y, 0) +
            sb(v4.y, 0) + sb(v5.y, 0) + sb(v6.y, 0) + sb(v7.y, 0);
      s5 += sb(v0.y, 8) + sb(v1.y, 8) + sb(v2.y, 8) + sb(v3.y, 8) +
            sb(v4.y, 8) + sb(v5.y, 8) + sb(v6.y, 8) + sb(v7.y, 8);
      s6 += sb(v0.y, 16) + sb(v1.y, 16) + sb(v2.y, 16) + sb(v3.y, 16) +
            sb(v4.y, 16) + sb(v5.y, 16) + sb(v6.y, 16) + sb(v7.y, 16);
      s7 += sb(v0.y, 24) + sb(v1.y, 24) + sb(v2.y, 24) + sb(v3.y, 24) +
            sb(v4.y, 24) + sb(v5.y, 24) + sb(v6.y, 24) + sb(v7.y, 24);
    }
    for (; k < cnt; ++k) {
      int r0 = __shfl(s, g * 8 + k);
      uint2 v0 = pp[(size_t)r0 * 8 + cl];
      s0 += sb(v0.x, 0); s1 += sb(v0.x, 8);
      s2 += sb(v0.x, 16); s3 += sb(v0.x, 24);
      s4 += sb(v0.y, 0); s5 += sb(v0.y, 8);
      s6 += sb(v0.y, 16); s7 += sb(v0.y, 24);
    }
  }
  if (cl < 5) {  // cols cl*8 .. cl*8+7 are real (40 cols total)
    float ma = *scl;
    float inv = deg > 0 ? ma / (127.f * (float)deg) : 0.f;
    float* op = out + (size_t)node * CLSN + cl * 8;
    float4 a0 = *reinterpret_cast<float4*>(op);
    float4 a1 = *reinterpret_cast<float4*>(op + 4);
    a0.x += (float)s0 * inv; a0.y += (float)s1 * inv;
    a0.z += (float)s2 * inv; a0.w += (float)s3 * inv;
    a1.x += (float)s4 * inv; a1.y += (float)s5 * inv;
    a1.z += (float)s6 * inv; a1.w += (float)s7 * inv;
    *reinterpret_cast<float4*>(op) = a0;
    *reinterpret_cast<float4*>(op + 4) = a1;
  }
}

extern "C" void kernel_launch(void* const* d_in, const int* in_sizes, int n_in,
                              void* d_out, int out_size, void* d_ws, size_t ws_size,
                              hipStream_t stream) {
  const float* x = (const float*)d_in[0];
  const int* ei = (const int*)d_in[1];
  const float* Wl1 = (const float*)d_in[2];
  const float* Wr1 = (const float*)d_in[3];
  const float* b1 = (const float*)d_in[4];
  const float* Wl2 = (const float*)d_in[5];
  const float* Wr2 = (const float*)d_in[6];
  const float* b2 = (const float*)d_in[7];
  float* out = (float*)d_out;

  const int n = in_sizes[0] / F;
  const int E = in_sizes[1] / 2;
  const int* src = ei;
  const int* dst = ei + E;

  const int nfine = (n + 511) >> 9;  // 196
  const int ngemm = (n + 63) / 64;   // 1563

  size_t off = 0;
  auto alloc = [&](size_t bytes) {
    size_t cur = off;
    off = (off + bytes + 255) & ~(size_t)255;
    return cur;
  };
  char* w = (char*)d_ws;
  int* offsets = (int*)(w + alloc((size_t)(n + 1) * 4));
  int* srcs = (int*)(w + alloc((size_t)E * 4));
  int* fcur = (int*)(w + alloc(NFINE_MAX * 4));
  float* scl = (float*)(w + alloc(256));
  float* bmax = (float*)(w + alloc((size_t)(ngemm + 8) * 4));
  ushort* xb = (ushort*)(w + alloc((size_t)n * F * 2));
  ushort* hb = (ushort*)(w + alloc((size_t)n * F * 2));
  ushort* meanb = (ushort*)(w + alloc((size_t)n * F * 2));
  ushort* Wp1 = (ushort*)(w + alloc(32768 * 2));
  ushort* Wp2l = (ushort*)(w + alloc(6144 * 2));
  ushort* Wp2r = (ushort*)(w + alloc(6144 * 2));
  (void)ws_size;
  // aliases (lifetime-disjoint, race-free):
  //   pairs (CSR build) -> meanb region (dead before agg_x writes mean)
  //   xq8 int8 [n][128] -> hb FIRST half (read by agg_x, dead before mfma1p)
  //   p64 bf16 [n][64]  -> hb SECOND half (written by mfma1p; NO overlap with meanb)
  //   pq8 int8 [n][64]  -> meanb second half (meanb dead after mfma1p staging)
  uint* pairs = (uint*)meanb;
  unsigned char* xq8 = (unsigned char*)hb;
  ushort* p64 = hb + (size_t)n * 64;
  unsigned char* pq8 = (unsigned char*)(meanb + (size_t)n * 64);

  const int castBlocks = (n * 32 + 255) / 256;

  // fused prep: cast x, pack W1/W2, init fcur
  k_prep<<<castBlocks + 23, 256, 0, stream>>>(x, xb, xq8, Wl1, Wr1, Wp1, Wl2, Wr2,
                                              Wp2l, Wp2r, fcur, n * 32, castBlocks,
                                              nfine);

  // binned CSR build
  k_partition<<<(E + TILE - 1) / TILE, 256, 0, stream>>>(src, dst, fcur, pairs, E);
  k_local_scatter<<<nfine, 256, 0, stream>>>(pairs, fcur, offsets, srcs, n, E, nfine);

  // layer 1: mean(x) via int8 gather -> fused h-GEMM + p-projection + root-GEMM
  k_agg_x<<<(n + 15) / 16, 256, 0, stream>>>(xq8, offsets, srcs, meanb, n);
  k_mfma1p<<<ngemm, 256, 0, stream>>>(meanb, xb, Wp1, b1, Wp2l, Wp2r, b2, p64,
                                      out, bmax, n);

  // layer 2 tail: scale; quantize p; gather-aggregate and accumulate into out
  k_scl<<<1, 256, 0, stream>>>(bmax, scl, ngemm);
  k_quant_p<<<(n * 16 + 255) / 256, 256, 0, stream>>>(p64, scl, pq8, n * 16);
  k_agg_add<<<(n + 31) / 32, 256, 0, stream>>>(pq8, offsets, srcs, scl, out, n);
}